// Round 4
// baseline (372.265 us; speedup 1.0000x reference)
//
#include <hip/hip_runtime.h>
#include <hip/hip_bf16.h>

// GCN layer: out = relu( (D^-1/2 A D^-1/2) @ (x @ W) ) over channel dim.
// B=16, C=64, S=2048, Fin=Fout=64.
#define B_ 16
#define C_ 64
#define S_ 2048
#define F_ 64
#define SF (S_ * F_)   // 131072, stride between channels
#define NS 8           // s-iterations per wave (software pipeline depth 1)

typedef __attribute__((ext_vector_type(8))) short short8;   // 8 bf16 (4 VGPRs) MFMA A/B frag
typedef __attribute__((ext_vector_type(4))) float float4_;  // MFMA C/D frag

// XOR-swizzle: spread 128B-stride rows across banks; keeps 8-elem groups contiguous
#define SWZ(row, col) ((col) ^ (((row) & 7) << 3))

__device__ __forceinline__ unsigned short f2bf(float f) {
    // RNE fp32->bf16 via integer ops (round-2 proven numerics)
    unsigned int u = __builtin_bit_cast(unsigned int, f);
    u += 0x7fffu + ((u >> 16) & 1u);
    return (unsigned short)(u >> 16);
}

__device__ __forceinline__ short8 pack8(float4_ u0, float4_ u1) {
    short8 a;
#pragma unroll
    for (int j = 0; j < 4; ++j) {
        a[j]     = (short)f2bf(u0[j]);
        a[4 + j] = (short)f2bf(u1[j]);
    }
    return a;
}

// ---------------------------------------------------------------------------
// Prep (round-2 proven): norm_adj -> bf16 [c][d];  wT[o][f] = bf16(weight[f][o])
// ---------------------------------------------------------------------------
__global__ void gcn_prep(const float* __restrict__ adj, const float* __restrict__ wgt,
                         unsigned short* __restrict__ nadj, unsigned short* __restrict__ wT)
{
    __shared__ float dis[C_];
    const int t = threadIdx.x;
    if (t < C_) {
        float s = 0.f;
        for (int d = 0; d < C_; ++d) s += adj[t * C_ + d];
        dis[t] = rsqrtf(s);
    }
    __syncthreads();
    for (int i = t; i < C_ * C_; i += 256) {
        const int c = i >> 6, d = i & 63;
        nadj[i] = f2bf(adj[i] * dis[c] * dis[d]);
        wT[d * F_ + c] = f2bf(wgt[i]);   // wgt[f=c][o=d] -> wT[o][f]
    }
}

// issue 8 nontemporal dwordx4 loads: half of one s-tile (2 d-tiles x full K)
__device__ __forceinline__ void load_half(float4_ (&R)[2][2][2], const float* xit,
                                          const int dtbase, const int lrow, const int lgrp)
{
#pragma unroll
    for (int dd = 0; dd < 2; ++dd) {
        const float* xr = xit + (size_t)((dtbase + dd) * 16 + lrow) * SF;
#pragma unroll
        for (int ks = 0; ks < 2; ++ks) {
            R[dd][ks][0] = __builtin_nontemporal_load((const float4_*)(xr + ks * 32 + lgrp * 8));
            R[dd][ks][1] = __builtin_nontemporal_load((const float4_*)(xr + ks * 32 + lgrp * 8 + 4));
        }
    }
}

// ---------------------------------------------------------------------------
// Main: 256-thread blocks (4 waves). Each wave loops over NS=8 s-values with
// split prefetch: next tile's loads issued in two halves while current tile
// computes (stage1 -> LDS transpose -> stage2 -> paired relu stores).
// ---------------------------------------------------------------------------
__global__ __launch_bounds__(256, 3) void gcn_main(
    const float* __restrict__ x,
    const unsigned short* __restrict__ nadj,
    const unsigned short* __restrict__ wT,
    float* __restrict__ out)
{
    __shared__ __align__(16) unsigned short lds_nadj[C_ * C_];   // 8 KB, swizzled
    __shared__ __align__(16) unsigned short lds_wT[F_ * F_];     // 8 KB, swizzled
    __shared__ __align__(16) unsigned short supT[4 * 16 * F_];   // 8 KB: per-wave 16 o-rows x 64 d

    const int tid  = threadIdx.x;
    const int w    = tid >> 6;          // wave id 0..3
    const int l    = tid & 63;
    const int lrow = l & 15;
    const int lgrp = l >> 4;            // 0..3

    // ---- cooperative fill of nadj/wT into swizzled LDS (2 x 16B per thread each)
    {
        const int fc = tid >> 2;          // row 0..63
        const int fd = (tid & 3) * 16;    // col base
        *(short8*)(lds_nadj + fc * 64 + SWZ(fc, fd))     = *(const short8*)(nadj + fc * 64 + fd);
        *(short8*)(lds_nadj + fc * 64 + SWZ(fc, fd + 8)) = *(const short8*)(nadj + fc * 64 + fd + 8);
        *(short8*)(lds_wT  + fc * 64 + SWZ(fc, fd))      = *(const short8*)(wT  + fc * 64 + fd);
        *(short8*)(lds_wT  + fc * 64 + SWZ(fc, fd + 8))  = *(const short8*)(wT  + fc * 64 + fd + 8);
    }
    __syncthreads();

    const int b     = blockIdx.x >> 6;    // 64 chunks per b
    const int chunk = blockIdx.x & 63;    // each chunk = 32 s (4 waves x 8 iters)
    const float* xbase = x   + (size_t)b * C_ * SF + (size_t)(chunk * 32 + w) * F_;
    float*       obase = out + (size_t)b * C_ * SF + (size_t)(chunk * 32 + w) * F_;
    unsigned short* myT = supT + w * (16 * F_);

    float4_ rA[2][2][2], rB[2][2][2];     // raw fp32 staging (32+32 VGPR)
    load_half(rA, xbase, 0, lrow, lgrp);
    load_half(rB, xbase, 2, lrow, lgrp);

#pragma unroll 1
    for (int i = 0; i < NS; ++i) {
        // ---- convert current tile (waits on its loads; issued >=1 iter ago)
        short8 af[4][2];
#pragma unroll
        for (int dd = 0; dd < 2; ++dd)
#pragma unroll
            for (int ks = 0; ks < 2; ++ks) {
                af[dd][ks]     = pack8(rA[dd][ks][0], rA[dd][ks][1]);
                af[2 + dd][ks] = pack8(rB[dd][ks][0], rB[dd][ks][1]);
            }

        const float* xnext = xbase + (size_t)(i + 1) * (4 * F_);
        float* ob = obase + (size_t)i * (4 * F_);

        // prefetch next tile, half A, before the compute phase
        if (i + 1 < NS) load_half(rA, xnext, 0, lrow, lgrp);

        float4_ keep[4];   // even-ot results held for paired (full-line) stores

        auto do_ot = [&](const int ot) {
            // W fragments for this o-tile (B-operand, stage 1)
            const int orow = ot * 16 + lrow;
            short8 wf0 = *(const short8*)(lds_wT + orow * 64 + SWZ(lrow, lgrp * 8));
            short8 wf1 = *(const short8*)(lds_wT + orow * 64 + SWZ(lrow, 32 + lgrp * 8));

            // Stage 1: sup[d][o] for this o-tile; write transposed+swizzled
#pragma unroll
            for (int dt = 0; dt < 4; ++dt) {
                float4_ s1 = {0.f, 0.f, 0.f, 0.f};
                s1 = __builtin_amdgcn_mfma_f32_16x16x32_bf16(af[dt][0], wf0, s1, 0, 0, 0);
                s1 = __builtin_amdgcn_mfma_f32_16x16x32_bf16(af[dt][1], wf1, s1, 0, 0, 0);
                const int dbase = dt * 16 + lgrp * 4;     // C-frag rows = d
                uint2 pk;                                  // lane's col = o = orow
                pk.x = (unsigned)f2bf(s1[0]) | ((unsigned)f2bf(s1[1]) << 16);
                pk.y = (unsigned)f2bf(s1[2]) | ((unsigned)f2bf(s1[3]) << 16);
                *(uint2*)(myT + lrow * 64 + SWZ(lrow, dbase)) = pk;
            }

            // sup^T fragments (A-operand, stage 2): row = o_local = lrow, k = d
            short8 bf0 = *(const short8*)(myT + lrow * 64 + SWZ(lrow, lgrp * 8));
            short8 bf1 = *(const short8*)(myT + lrow * 64 + SWZ(lrow, 32 + lgrp * 8));

            // Stage 2: out[c][o], transposed compute -> lane holds 4 contiguous o
#pragma unroll
            for (int ct = 0; ct < 4; ++ct) {
                const int crow = ct * 16 + lrow;
                short8 an0 = *(const short8*)(lds_nadj + crow * 64 + SWZ(lrow, lgrp * 8));
                short8 an1 = *(const short8*)(lds_nadj + crow * 64 + SWZ(lrow, 32 + lgrp * 8));
                float4_ acc = {0.f, 0.f, 0.f, 0.f};
                acc = __builtin_amdgcn_mfma_f32_16x16x32_bf16(bf0, an0, acc, 0, 0, 0);
                acc = __builtin_amdgcn_mfma_f32_16x16x32_bf16(bf1, an1, acc, 0, 0, 0);
                float4_ r;
#pragma unroll
                for (int j = 0; j < 4; ++j) r[j] = fmaxf(acc[j], 0.f);
                if (ot & 1) {
                    // store even+odd halves of each 128B line back-to-back
                    __builtin_nontemporal_store(keep[ct],
                        (float4_*)(ob + (size_t)crow * SF + (ot - 1) * 16 + lgrp * 4));
                    __builtin_nontemporal_store(r,
                        (float4_*)(ob + (size_t)crow * SF + ot * 16 + lgrp * 4));
                } else {
                    keep[ct] = r;
                }
            }
        };

        do_ot(0);
        do_ot(1);
        // prefetch next tile, half B, between the two ot-pairs
        if (i + 1 < NS) load_half(rB, xnext, 2, lrow, lgrp);
        do_ot(2);
        do_ot(3);
    }
}

// ---------------------------------------------------------------------------
extern "C" void kernel_launch(void* const* d_in, const int* in_sizes, int n_in,
                              void* d_out, int out_size, void* d_ws, size_t ws_size,
                              hipStream_t stream) {
    const float* x   = (const float*)d_in[0];
    const float* adj = (const float*)d_in[1];
    const float* wgt = (const float*)d_in[2];
    float* out = (float*)d_out;

    unsigned short* nadj = (unsigned short*)d_ws;      // 4096 bf16
    unsigned short* wT   = nadj + C_ * C_;             // 4096 bf16

    gcn_prep<<<1, 256, 0, stream>>>(adj, wgt, nadj, wT);

    dim3 grid(B_ * (S_ / 32));   // 1024 blocks: (b, chunk of 32 s)
    gcn_main<<<grid, 256, 0, stream>>>(x, nadj, wT, out);
}

// Round 5
// 353.424 us; speedup vs baseline: 1.0533x; 1.0533x over previous
//
#include <hip/hip_runtime.h>
#include <hip/hip_bf16.h>

// GCN layer: out = relu( (D^-1/2 A D^-1/2) @ (x @ W) ) over channel dim.
// B=16, C=64, S=2048, Fin=Fout=64.
#define B_ 16
#define C_ 64
#define S_ 2048
#define F_ 64
#define SF (S_ * F_)   // 131072, stride between channels

typedef __attribute__((ext_vector_type(8))) short short8;   // 8 bf16 (4 VGPRs) MFMA A/B frag
typedef __attribute__((ext_vector_type(4))) float float4_;  // MFMA C/D frag

// XOR-swizzle: spread 128B-stride rows across banks; keeps 8-elem groups contiguous
#define SWZ(row, col) ((col) ^ (((row) & 7) << 3))

__device__ __forceinline__ unsigned short f2bf(float f) {
    // RNE fp32->bf16 via integer ops (round-2 proven numerics)
    unsigned int u = __builtin_bit_cast(unsigned int, f);
    u += 0x7fffu + ((u >> 16) & 1u);
    return (unsigned short)(u >> 16);
}

// ---------------------------------------------------------------------------
// Prep (round-2 proven): norm_adj -> bf16 [c][d];  wT[o][f] = bf16(weight[f][o])
// ---------------------------------------------------------------------------
__global__ void gcn_prep(const float* __restrict__ adj, const float* __restrict__ wgt,
                         unsigned short* __restrict__ nadj, unsigned short* __restrict__ wT)
{
    __shared__ float dis[C_];
    const int t = threadIdx.x;
    if (t < C_) {
        float s = 0.f;
        for (int d = 0; d < C_; ++d) s += adj[t * C_ + d];
        dis[t] = rsqrtf(s);
    }
    __syncthreads();
    for (int i = t; i < C_ * C_; i += 256) {
        const int c = i >> 6, d = i & 63;
        nadj[i] = f2bf(adj[i] * dis[c] * dis[d]);
        wT[d * F_ + c] = f2bf(wgt[i]);   // wgt[f=c][o=d] -> wT[o][f]
    }
}

// ---------------------------------------------------------------------------
// Main: one block = (b, 8 consecutive s); one wave = one s. One-shot per wave.
// Stage 1: sup[d][o] = x[b,d,s,:] @ W        (A = x rows, B = W)
// Stage 2 (transposed): mfma(sup^T frags, nadj rows) -> lane holds
//          out[c=lrow][o=lgrp*4+i]. ot-tiles processed in PAIRS so each
//          128B out-line is written by two back-to-back float4 stores
//          (normal cached stores -> L2 merges -> full-line writeback).
// ---------------------------------------------------------------------------
__global__ __launch_bounds__(512, 6) void gcn_main(
    const float* __restrict__ x,
    const unsigned short* __restrict__ nadj,
    const unsigned short* __restrict__ wT,
    float* __restrict__ out)
{
    __shared__ __align__(16) unsigned short lds_nadj[C_ * C_];   // 8 KB, swizzled
    __shared__ __align__(16) unsigned short lds_wT[F_ * F_];     // 8 KB, swizzled
    __shared__ __align__(16) unsigned short supT[8 * 32 * F_];   // 32 KB: per-wave 32 o-rows x 64 d

    const int tid  = threadIdx.x;
    const int w    = tid >> 6;          // wave id 0..7  == s within tile
    const int l    = tid & 63;
    const int lrow = l & 15;
    const int lgrp = l >> 4;            // 0..3

    // ---- cooperative fill of nadj/wT into swizzled LDS (16B per thread each)
    {
        const int fc = tid >> 3;          // row 0..63
        const int fd = (tid & 7) * 8;     // col base
        *(short8*)(lds_nadj + fc * 64 + SWZ(fc, fd)) = *(const short8*)(nadj + fc * 64 + fd);
        *(short8*)(lds_wT  + fc * 64 + SWZ(fc, fd)) = *(const short8*)(wT  + fc * 64 + fd);
    }
    __syncthreads();

    const int b  = blockIdx.x >> 8;     // 256 s-tiles per b
    const int st = blockIdx.x & 255;
    const int s  = st * 8 + w;

    // ---- load x A-fragments for all 64 channels (nontemporal; fp32 -> bf16)
    const float* xb = x + (size_t)b * C_ * SF + (size_t)s * F_;
    short8 af[4][2];
#pragma unroll
    for (int dt = 0; dt < 4; ++dt) {
        const float* xr = xb + (size_t)(dt * 16 + lrow) * SF;
#pragma unroll
        for (int ks = 0; ks < 2; ++ks) {
            float4_ u0 = __builtin_nontemporal_load((const float4_*)(xr + ks * 32 + lgrp * 8));
            float4_ u1 = __builtin_nontemporal_load((const float4_*)(xr + ks * 32 + lgrp * 8 + 4));
            short8 a;
#pragma unroll
            for (int j = 0; j < 4; ++j) {
                a[j]     = (short)f2bf(u0[j]);
                a[4 + j] = (short)f2bf(u1[j]);
            }
            af[dt][ks] = a;
        }
    }

    unsigned short* myT = supT + w * (32 * F_);
    float* ob = out + (size_t)b * C_ * SF + (size_t)s * F_;

#pragma unroll 1
    for (int p = 0; p < 2; ++p) {
        // ---- Stage 1 for ot pair {2p, 2p+1}: fill 32 o-rows of supT
#pragma unroll
        for (int par = 0; par < 2; ++par) {
            const int ot = 2 * p + par;
            const int orow = ot * 16 + lrow;
            short8 wf0 = *(const short8*)(lds_wT + orow * 64 + SWZ(lrow, lgrp * 8));
            short8 wf1 = *(const short8*)(lds_wT + orow * 64 + SWZ(lrow, 32 + lgrp * 8));
            unsigned short* tT = myT + par * (16 * F_);
#pragma unroll
            for (int dt = 0; dt < 4; ++dt) {
                float4_ s1 = {0.f, 0.f, 0.f, 0.f};
                s1 = __builtin_amdgcn_mfma_f32_16x16x32_bf16(af[dt][0], wf0, s1, 0, 0, 0);
                s1 = __builtin_amdgcn_mfma_f32_16x16x32_bf16(af[dt][1], wf1, s1, 0, 0, 0);
                const int dbase = dt * 16 + lgrp * 4;     // C-frag rows = d
                uint2 pk;                                  // lane's col = o = orow
                pk.x = (unsigned)f2bf(s1[0]) | ((unsigned)f2bf(s1[1]) << 16);
                pk.y = (unsigned)f2bf(s1[2]) | ((unsigned)f2bf(s1[3]) << 16);
                *(uint2*)(tT + lrow * 64 + SWZ(lrow, dbase)) = pk;
            }
        }

        // ---- Stage 2 for the pair: sup^T fragments (A-operand), nadj (B-operand)
        short8 be0 = *(const short8*)(myT + lrow * 64 + SWZ(lrow, lgrp * 8));
        short8 be1 = *(const short8*)(myT + lrow * 64 + SWZ(lrow, 32 + lgrp * 8));
        short8 bo0 = *(const short8*)(myT + (16 * F_) + lrow * 64 + SWZ(lrow, lgrp * 8));
        short8 bo1 = *(const short8*)(myT + (16 * F_) + lrow * 64 + SWZ(lrow, 32 + lgrp * 8));

#pragma unroll
        for (int ct = 0; ct < 4; ++ct) {
            const int crow = ct * 16 + lrow;
            short8 an0 = *(const short8*)(lds_nadj + crow * 64 + SWZ(lrow, lgrp * 8));
            short8 an1 = *(const short8*)(lds_nadj + crow * 64 + SWZ(lrow, 32 + lgrp * 8));

            float4_ ae = {0.f, 0.f, 0.f, 0.f};
            ae = __builtin_amdgcn_mfma_f32_16x16x32_bf16(be0, an0, ae, 0, 0, 0);
            ae = __builtin_amdgcn_mfma_f32_16x16x32_bf16(be1, an1, ae, 0, 0, 0);
            float4_ ao = {0.f, 0.f, 0.f, 0.f};
            ao = __builtin_amdgcn_mfma_f32_16x16x32_bf16(bo0, an0, ao, 0, 0, 0);
            ao = __builtin_amdgcn_mfma_f32_16x16x32_bf16(bo1, an1, ao, 0, 0, 0);

            float4_ re, ro;
#pragma unroll
            for (int j = 0; j < 4; ++j) {
                re[j] = fmaxf(ae[j], 0.f);
                ro[j] = fmaxf(ao[j], 0.f);
            }
            // lane covers out[c=crow][o = p*32 (+16) + lgrp*4 + j]; the two
            // stores land in the same 128B line back-to-back.
            float* dst = ob + (size_t)crow * SF + p * 32 + lgrp * 4;
            *(float4_*)(dst)      = re;
            *(float4_*)(dst + 16) = ro;
        }
    }
}

// ---------------------------------------------------------------------------
extern "C" void kernel_launch(void* const* d_in, const int* in_sizes, int n_in,
                              void* d_out, int out_size, void* d_ws, size_t ws_size,
                              hipStream_t stream) {
    const float* x   = (const float*)d_in[0];
    const float* adj = (const float*)d_in[1];
    const float* wgt = (const float*)d_in[2];
    float* out = (float*)d_out;

    unsigned short* nadj = (unsigned short*)d_ws;      // 4096 bf16
    unsigned short* wT   = nadj + C_ * C_;             // 4096 bf16

    gcn_prep<<<1, 256, 0, stream>>>(adj, wgt, nadj, wT);

    dim3 grid(B_ * (S_ / 8));   // 4096 blocks: (b, s-tile of 8)
    gcn_main<<<grid, 512, 0, stream>>>(x, nadj, wT, out);
}

// Round 6
// 219.248 us; speedup vs baseline: 1.6979x; 1.6120x over previous
//
#include <hip/hip_runtime.h>
#include <hip/hip_bf16.h>

// GCN layer: out = relu( (D^-1/2 A D^-1/2) @ (x @ W) ) over channel dim.
// B=16, C=64, S=2048, Fin=Fout=64.
#define B_ 16
#define C_ 64
#define S_ 2048
#define F_ 64
#define SF (S_ * F_)   // 131072, stride between channels

typedef __attribute__((ext_vector_type(8))) short short8;   // 8 bf16 (4 VGPRs) MFMA A/B frag
typedef __attribute__((ext_vector_type(4))) float float4_;  // MFMA C/D frag

// XOR-swizzle for bf16 tiles: spread 128B-stride rows; keeps 8-elem groups contiguous
#define SWZ(row, col) ((col) ^ (((row) & 7) << 3))

__device__ __forceinline__ unsigned short f2bf(float f) {
    // RNE fp32->bf16 via integer ops (proven numerics)
    unsigned int u = __builtin_bit_cast(unsigned int, f);
    u += 0x7fffu + ((u >> 16) & 1u);
    return (unsigned short)(u >> 16);
}

// ---------------------------------------------------------------------------
// Prep (proven): norm_adj -> bf16 [c][d];  wT[o][f] = bf16(weight[f][o])
// ---------------------------------------------------------------------------
__global__ void gcn_prep(const float* __restrict__ adj, const float* __restrict__ wgt,
                         unsigned short* __restrict__ nadj, unsigned short* __restrict__ wT)
{
    __shared__ float dis[C_];
    const int t = threadIdx.x;
    if (t < C_) {
        float s = 0.f;
        for (int d = 0; d < C_; ++d) s += adj[t * C_ + d];
        dis[t] = rsqrtf(s);
    }
    __syncthreads();
    for (int i = t; i < C_ * C_; i += 256) {
        const int c = i >> 6, d = i & 63;
        nadj[i] = f2bf(adj[i] * dis[c] * dis[d]);
        wT[d * F_ + c] = f2bf(wgt[i]);   // wgt[f=c][o=d] -> wT[o][f]
    }
}

// ---------------------------------------------------------------------------
// Main: one block = (b, 8 consecutive s); one wave = one s (round-2 skeleton).
// Stage 1: sup[d][o] = x[b,d,s,:] @ W ; per-ot transpose via wave-local supT,
//          A-frags (sup^T rows) pulled to registers  -> supT region dies.
// Stage 2: out[c][o] via mfma(supT-frags, nadj rows); relu; results staged in
//          a 32KB LDS out-tile (union with supT), then cooperatively stored as
//          2KB fully-contiguous nontemporal runs (complete 128B lines only).
// ---------------------------------------------------------------------------
__global__ __launch_bounds__(512, 4) void gcn_main(
    const float* __restrict__ x,
    const unsigned short* __restrict__ nadj,
    const unsigned short* __restrict__ wT,
    float* __restrict__ out)
{
    __shared__ __align__(16) unsigned short lds_nadj[C_ * C_];   // 8 KB, swizzled
    __shared__ __align__(16) unsigned short lds_wT[F_ * F_];     // 8 KB, swizzled
    // union: stage1 per-wave supT (8 x 2KB = 16KB) OR stage2 out-tile fp32[16][512] (32KB)
    __shared__ __align__(16) unsigned char u_mem[32768];

    const int tid  = threadIdx.x;
    const int w    = tid >> 6;          // wave id 0..7  == s within tile
    const int l    = tid & 63;
    const int lrow = l & 15;
    const int lgrp = l >> 4;            // 0..3

    // ---- cooperative fill of nadj/wT into swizzled LDS (16B per thread each)
    {
        const int fc = tid >> 3;          // row 0..63
        const int fd = (tid & 7) * 8;     // col base
        *(short8*)(lds_nadj + fc * 64 + SWZ(fc, fd)) = *(const short8*)(nadj + fc * 64 + fd);
        *(short8*)(lds_wT  + fc * 64 + SWZ(fc, fd)) = *(const short8*)(wT  + fc * 64 + fd);
    }
    __syncthreads();

    const int b  = blockIdx.x >> 8;     // 256 s-tiles per b
    const int st = blockIdx.x & 255;
    const int s  = st * 8 + w;

    // ---- load x A-fragments for all 64 channels (nontemporal; fp32 -> bf16)
    const float* xb = x + (size_t)b * C_ * SF + (size_t)s * F_;
    short8 af[4][2];
#pragma unroll
    for (int dt = 0; dt < 4; ++dt) {
        const float* xr = xb + (size_t)(dt * 16 + lrow) * SF;
#pragma unroll
        for (int ks = 0; ks < 2; ++ks) {
            float4_ u0 = __builtin_nontemporal_load((const float4_*)(xr + ks * 32 + lgrp * 8));
            float4_ u1 = __builtin_nontemporal_load((const float4_*)(xr + ks * 32 + lgrp * 8 + 4));
            short8 a;
#pragma unroll
            for (int j = 0; j < 4; ++j) {
                a[j]     = (short)f2bf(u0[j]);
                a[4 + j] = (short)f2bf(u1[j]);
            }
            af[dt][ks] = a;
        }
    }

    unsigned short* myT = (unsigned short*)u_mem + w * (16 * F_);  // wave-local 2KB
    float* obuf = (float*)u_mem;                                   // stage2: [16][512] fp32

    // ---- Stage 1: per o-tile, sup[d][o] -> wave-local transpose -> A-frags in regs
    short8 aA[4][2];
#pragma unroll
    for (int ot = 0; ot < 4; ++ot) {
        const int orow = ot * 16 + lrow;
        short8 wf0 = *(const short8*)(lds_wT + orow * 64 + SWZ(lrow, lgrp * 8));
        short8 wf1 = *(const short8*)(lds_wT + orow * 64 + SWZ(lrow, 32 + lgrp * 8));
#pragma unroll
        for (int dt = 0; dt < 4; ++dt) {
            float4_ s1 = {0.f, 0.f, 0.f, 0.f};
            s1 = __builtin_amdgcn_mfma_f32_16x16x32_bf16(af[dt][0], wf0, s1, 0, 0, 0);
            s1 = __builtin_amdgcn_mfma_f32_16x16x32_bf16(af[dt][1], wf1, s1, 0, 0, 0);
            const int dbase = dt * 16 + lgrp * 4;     // C-frag rows = d
            uint2 pk;                                  // lane's col = o = orow
            pk.x = (unsigned)f2bf(s1[0]) | ((unsigned)f2bf(s1[1]) << 16);
            pk.y = (unsigned)f2bf(s1[2]) | ((unsigned)f2bf(s1[3]) << 16);
            *(uint2*)(myT + lrow * 64 + SWZ(lrow, dbase)) = pk;
        }
        // sup^T fragments (A-operand, stage 2): row = o_local = lrow, k = d
        aA[ot][0] = *(const short8*)(myT + lrow * 64 + SWZ(lrow, lgrp * 8));
        aA[ot][1] = *(const short8*)(myT + lrow * 64 + SWZ(lrow, 32 + lgrp * 8));
    }
    __syncthreads();   // supT regions dead everywhere; obuf may now be written

    // ---- Stage 2: per c-tile, all 64 o; relu; stage in obuf; coop full-line store
#pragma unroll 1
    for (int ct = 0; ct < 4; ++ct) {
        const int crow = ct * 16 + lrow;
        short8 an0 = *(const short8*)(lds_nadj + crow * 64 + SWZ(lrow, lgrp * 8));
        short8 an1 = *(const short8*)(lds_nadj + crow * 64 + SWZ(lrow, 32 + lgrp * 8));
#pragma unroll
        for (int ot = 0; ot < 4; ++ot) {
            float4_ acc = {0.f, 0.f, 0.f, 0.f};
            acc = __builtin_amdgcn_mfma_f32_16x16x32_bf16(aA[ot][0], an0, acc, 0, 0, 0);
            acc = __builtin_amdgcn_mfma_f32_16x16x32_bf16(aA[ot][1], an1, acc, 0, 0, 0);
            float4_ r;
#pragma unroll
            for (int j = 0; j < 4; ++j) r[j] = fmaxf(acc[j], 0.f);
            // lane holds out[c = crow][o = ot*16 + lgrp*4 + j] for s = w.
            // obuf[cl][col], col = w*64 + o, dword-col swizzled by (cl&7)*4.
            const int col = w * 64 + ot * 16 + lgrp * 4;
            *(float4_*)(obuf + lrow * 512 + (col ^ ((lrow & 7) * 4))) = r;
        }
        __syncthreads();   // out-tile complete for this ct

        // cooperative store: 16 c-rows x 2KB contiguous; 32 wave-instr tasks
#pragma unroll
        for (int t = 0; t < 4; ++t) {
            const int task = w * 4 + t;          // 0..31
            const int cl    = task >> 1;         // c-local 0..15
            const int half  = task & 1;          // which 1KB half
            const int col   = half * 256 + l * 4;
            float4_ v = *(const float4_*)(obuf + cl * 512 + (col ^ ((cl & 7) * 4)));
            float* g = out + (((size_t)(b * C_ + ct * 16 + cl) * S_ + st * 8) * F_) + col;
            __builtin_nontemporal_store(v, (float4_*)g);
        }
        if (ct < 3) __syncthreads();   // protect obuf reuse by next ct
    }
}

// ---------------------------------------------------------------------------
extern "C" void kernel_launch(void* const* d_in, const int* in_sizes, int n_in,
                              void* d_out, int out_size, void* d_ws, size_t ws_size,
                              hipStream_t stream) {
    const float* x   = (const float*)d_in[0];
    const float* adj = (const float*)d_in[1];
    const float* wgt = (const float*)d_in[2];
    float* out = (float*)d_out;

    unsigned short* nadj = (unsigned short*)d_ws;      // 4096 bf16
    unsigned short* wT   = nadj + C_ * C_;             // 4096 bf16

    gcn_prep<<<1, 256, 0, stream>>>(adj, wgt, nadj, wT);

    dim3 grid(B_ * (S_ / 8));   // 4096 blocks: (b, s-tile of 8)
    gcn_main<<<grid, 512, 0, stream>>>(x, nadj, wT, out);
}

// Round 7
// 208.196 us; speedup vs baseline: 1.7880x; 1.0531x over previous
//
#include <hip/hip_runtime.h>
#include <hip/hip_bf16.h>

// GCN layer: out = relu( (D^-1/2 A D^-1/2) @ (x @ W) ) over channel dim.
// B=16, C=64, S=2048, Fin=Fout=64.
#define B_ 16
#define C_ 64
#define S_ 2048
#define F_ 64
#define SF (S_ * F_)   // 131072, stride between channels

typedef __attribute__((ext_vector_type(8))) short short8;   // 8 bf16 (4 VGPRs) MFMA A/B frag
typedef __attribute__((ext_vector_type(4))) float float4_;  // MFMA C/D frag

// bf16-tile XOR-swizzle (halfword units, 16B granules)
#define SWZ(row, col) ((col) ^ (((row) & 7) << 3))
// fp32-tile XOR-swizzle (dword units, 16B granules)
#define SWZ4(row, col) ((col) ^ (((row) & 7) << 2))

__device__ __forceinline__ unsigned short f2bf(float f) {
    // RNE fp32->bf16 via integer ops (proven numerics)
    unsigned int u = __builtin_bit_cast(unsigned int, f);
    u += 0x7fffu + ((u >> 16) & 1u);
    return (unsigned short)(u >> 16);
}

// ---------------------------------------------------------------------------
// Prep (proven): norm_adj -> bf16 [c][d];  wT[o][f] = bf16(weight[f][o])
// ---------------------------------------------------------------------------
__global__ void gcn_prep(const float* __restrict__ adj, const float* __restrict__ wgt,
                         unsigned short* __restrict__ nadj, unsigned short* __restrict__ wT)
{
    __shared__ float dis[C_];
    const int t = threadIdx.x;
    if (t < C_) {
        float s = 0.f;
        for (int d = 0; d < C_; ++d) s += adj[t * C_ + d];
        dis[t] = rsqrtf(s);
    }
    __syncthreads();
    for (int i = t; i < C_ * C_; i += 256) {
        const int c = i >> 6, d = i & 63;
        nadj[i] = f2bf(adj[i] * dis[c] * dis[d]);
        wT[d * F_ + c] = f2bf(wgt[i]);   // wgt[f=c][o=d] -> wT[o][f]
    }
}

// ---------------------------------------------------------------------------
// Main: one block = (b, 8 consecutive s); one wave = one s. After the table
// fill there are NO block barriers: each wave stages through its private 4KB
// LDS tile and issues fire-and-forget nontemporal full-line stores.
// Stage 1: sup[d][o] = x[b,d,s,:] @ W ; per-ot wave-local transpose -> aA regs.
// Stage 2: per ct (16 c-rows): mfma(aA, nadj) -> relu -> swizzled LDS tile ->
//          read back as 4 store-instrs, each 4 x 256B contiguous runs.
// ---------------------------------------------------------------------------
__global__ __launch_bounds__(512, 4) void gcn_main(
    const float* __restrict__ x,
    const unsigned short* __restrict__ nadj,
    const unsigned short* __restrict__ wT,
    float* __restrict__ out)
{
    __shared__ __align__(16) unsigned short lds_nadj[C_ * C_];   // 8 KB, swizzled
    __shared__ __align__(16) unsigned short lds_wT[F_ * F_];     // 8 KB, swizzled
    __shared__ __align__(16) float obuf_all[8][16 * 64];         // 4 KB per wave (unions supT)

    const int tid  = threadIdx.x;
    const int w    = tid >> 6;          // wave id 0..7  == s within tile
    const int l    = tid & 63;
    const int lrow = l & 15;
    const int lgrp = l >> 4;            // 0..3

    // ---- cooperative fill of nadj/wT into swizzled LDS (16B per thread each)
    {
        const int fc = tid >> 3;          // row 0..63
        const int fd = (tid & 7) * 8;     // col base
        *(short8*)(lds_nadj + fc * 64 + SWZ(fc, fd)) = *(const short8*)(nadj + fc * 64 + fd);
        *(short8*)(lds_wT  + fc * 64 + SWZ(fc, fd)) = *(const short8*)(wT  + fc * 64 + fd);
    }
    __syncthreads();    // the only block barrier

    const int b  = blockIdx.x >> 8;     // 256 s-tiles per b
    const int st = blockIdx.x & 255;
    const int s  = st * 8 + w;

    // ---- load x A-fragments for all 64 channels (nontemporal; fp32 -> bf16)
    const float* xb = x + (size_t)b * C_ * SF + (size_t)s * F_;
    short8 af[4][2];
#pragma unroll
    for (int dt = 0; dt < 4; ++dt) {
        const float* xr = xb + (size_t)(dt * 16 + lrow) * SF;
#pragma unroll
        for (int ks = 0; ks < 2; ++ks) {
            float4_ u0 = __builtin_nontemporal_load((const float4_*)(xr + ks * 32 + lgrp * 8));
            float4_ u1 = __builtin_nontemporal_load((const float4_*)(xr + ks * 32 + lgrp * 8 + 4));
            short8 a;
#pragma unroll
            for (int j = 0; j < 4; ++j) {
                a[j]     = (short)f2bf(u0[j]);
                a[4 + j] = (short)f2bf(u1[j]);
            }
            af[dt][ks] = a;
        }
    }

    float* myO = obuf_all[w];                       // fp32 [16][64] view (stage 2)
    unsigned short* myT = (unsigned short*)myO;     // bf16 [16][64] view (stage 1, first 2KB)

    // ---- Stage 1: per o-tile, sup[d][o] -> wave-local transpose -> aA regs
    short8 aA[4][2];
#pragma unroll
    for (int ot = 0; ot < 4; ++ot) {
        const int orow = ot * 16 + lrow;
        short8 wf0 = *(const short8*)(lds_wT + orow * 64 + SWZ(lrow, lgrp * 8));
        short8 wf1 = *(const short8*)(lds_wT + orow * 64 + SWZ(lrow, 32 + lgrp * 8));
#pragma unroll
        for (int dt = 0; dt < 4; ++dt) {
            float4_ s1 = {0.f, 0.f, 0.f, 0.f};
            s1 = __builtin_amdgcn_mfma_f32_16x16x32_bf16(af[dt][0], wf0, s1, 0, 0, 0);
            s1 = __builtin_amdgcn_mfma_f32_16x16x32_bf16(af[dt][1], wf1, s1, 0, 0, 0);
            const int dbase = dt * 16 + lgrp * 4;     // C-frag rows = d
            uint2 pk;                                  // lane's col = o = orow
            pk.x = (unsigned)f2bf(s1[0]) | ((unsigned)f2bf(s1[1]) << 16);
            pk.y = (unsigned)f2bf(s1[2]) | ((unsigned)f2bf(s1[3]) << 16);
            *(uint2*)(myT + lrow * 64 + SWZ(lrow, dbase)) = pk;
        }
        // sup^T fragments (A-operand, stage 2): row = o_local = lrow, k = d
        aA[ot][0] = *(const short8*)(myT + lrow * 64 + SWZ(lrow, lgrp * 8));
        aA[ot][1] = *(const short8*)(myT + lrow * 64 + SWZ(lrow, 32 + lgrp * 8));
    }
    // (myT region dead once aA loaded; within-wave lgkmcnt ordering protects reuse)

    // ---- Stage 2: per c-tile: MFMA -> relu -> private LDS tile -> full-line NT stores
#pragma unroll 1
    for (int ct = 0; ct < 4; ++ct) {
        const int crow = ct * 16 + lrow;
        short8 an0 = *(const short8*)(lds_nadj + crow * 64 + SWZ(lrow, lgrp * 8));
        short8 an1 = *(const short8*)(lds_nadj + crow * 64 + SWZ(lrow, 32 + lgrp * 8));

#pragma unroll
        for (int ot = 0; ot < 4; ++ot) {
            float4_ acc = {0.f, 0.f, 0.f, 0.f};
            acc = __builtin_amdgcn_mfma_f32_16x16x32_bf16(aA[ot][0], an0, acc, 0, 0, 0);
            acc = __builtin_amdgcn_mfma_f32_16x16x32_bf16(aA[ot][1], an1, acc, 0, 0, 0);
            float4_ r;
#pragma unroll
            for (int j = 0; j < 4; ++j) r[j] = fmaxf(acc[j], 0.f);
            // lane holds out[c=crow][o = ot*16 + lgrp*4 + j]; stage in own tile,
            // dword-col swizzled (conflict-free per 8-lane phase)
            *(float4_*)(myO + lrow * 64 + SWZ4(lrow, ot * 16 + lgrp * 4)) = r;
        }

        // read back + store: 4 instrs, each = 4 c-rows x 256B contiguous runs
#pragma unroll
        for (int t = 0; t < 4; ++t) {
            const int cl  = t * 4 + (l >> 4);       // c-local 0..15
            const int col = (l & 15) * 4;           // dword col 0..60
            float4_ v = *(const float4_*)(myO + cl * 64 + SWZ4(cl, col));
            float* g = out + ((size_t)(b * C_ + ct * 16 + cl) * S_ + s) * F_ + col;
            __builtin_nontemporal_store(v, (float4_*)g);
        }
    }
}

// ---------------------------------------------------------------------------
extern "C" void kernel_launch(void* const* d_in, const int* in_sizes, int n_in,
                              void* d_out, int out_size, void* d_ws, size_t ws_size,
                              hipStream_t stream) {
    const float* x   = (const float*)d_in[0];
    const float* adj = (const float*)d_in[1];
    const float* wgt = (const float*)d_in[2];
    float* out = (float*)d_out;

    unsigned short* nadj = (unsigned short*)d_ws;      // 4096 bf16
    unsigned short* wT   = nadj + C_ * C_;             // 4096 bf16

    gcn_prep<<<1, 256, 0, stream>>>(adj, wgt, nadj, wT);

    dim3 grid(B_ * (S_ / 8));   // 4096 blocks: (b, s-tile of 8)
    gcn_main<<<grid, 512, 0, stream>>>(x, nadj, wT, out);
}